// Round 3
// baseline (256.619 us; speedup 1.0000x reference)
//
#include <hip/hip_runtime.h>

// ---------------------------------------------------------------------------
// StickyHDPHMMVI emission log-likelihood, MFMA formulation:
// out[bt,k] = c0_k - 0.5 * sum_x A[bt,x] * B[k,x]
//   x in [0,4096): A = S0_bt[d,e] (mu muT + F FT), B = E_k[d,e]
//   x in [4096,4160): A = mu[d],  B = -2*v_k[d]      (v = E mu_k)
//   x in [4160,4224): A = var[d], B = E_k[d,d]       (diag trace term)
// flattening: x = (e>>5)*2048 + d*32 + (e&31)
// prep: Gauss-Jordan on [Psi | I] (parallel), logdet from pivots
// main: no LDS, A-fragments built in registers from global f32 inputs
// ---------------------------------------------------------------------------

#define KDIM 4224
#define NROW 48
#define BT_TOTAL 32768

typedef __attribute__((ext_vector_type(8))) short bf16x8;
typedef __attribute__((ext_vector_type(8))) __bf16 bfv8;
typedef __attribute__((ext_vector_type(4))) float f32x4;

__device__ __forceinline__ short f2bf_hw(float f){
  __bf16 h = (__bf16)f;
  return __builtin_bit_cast(short, h);
}

__device__ __forceinline__ float digammaf_(float x){
  float r = 0.f;
  while (x < 6.f){ r -= 1.f / x; x += 1.f; }
  float xi = 1.f / x;
  float xi2 = xi * xi;
  return r + logf(x) - 0.5f * xi
         - xi2 * (0.083333333333f - xi2 * (0.0083333333333f - xi2 * 0.0039682539683f));
}

__device__ __forceinline__ float wsum64(float x){
  #pragma unroll
  for (int o = 32; o > 0; o >>= 1) x += __shfl_down(x, o);
  return x;  // valid in lane 0
}

// --------------------- kernel A: per-k prep (Gauss-Jordan) ------------------
__global__ __launch_bounds__(256) void prep_kernel(
    const float* __restrict__ mu_k, const float* __restrict__ Psi,
    const float* __restrict__ nu_a, const float* __restrict__ kap_a,
    short* __restrict__ Ebf, float* __restrict__ c0o)
{
  const int k = blockIdx.x;
  const int tid = threadIdx.x;
  short* Erow = Ebf + (size_t)k * KDIM;
  if (k >= 33){
    for (int i = tid; i < KDIM; i += 256) Erow[i] = 0;
    if (tid == 0) c0o[k] = 0.f;
    return;
  }
  __shared__ float W[64][129];   // [row][0:64)=Psi, [64:128)=I ; pad->2-way max
  __shared__ float muk[64];
  __shared__ float dinv[64];

  const int row = tid & 63;          // each wave owns all 64 rows
  const int c0 = (tid >> 6) << 5;    // column block 0/32/64/96

  for (int i = tid; i < 4096; i += 256) W[i >> 6][i & 63] = Psi[(size_t)k * 4096 + i];
  for (int i = tid; i < 4096; i += 256){
    int r = i >> 6, c = i & 63;
    W[r][64 + c] = (r == c) ? 1.f : 0.f;
  }
  if (tid < 64) muk[tid] = mu_k[k * 64 + tid];
  __syncthreads();

  float ldsum = 0.f;
  for (int j = 0; j < 64; ++j){
    float pivot = W[j][j];
    float f = W[row][j] * __builtin_amdgcn_rcpf(pivot);
    ldsum += logf(pivot);
    __syncthreads();                 // reads of col j / pivot done
    if (row != j){
      #pragma unroll 8
      for (int c = 0; c < 32; ++c)
        W[row][c0 + c] = fmaf(-f, W[j][c0 + c], W[row][c0 + c]);
    }
    __syncthreads();                 // updates visible for next pivot
  }

  const float nu = nu_a[k];
  if (tid < 64) dinv[tid] = nu * __builtin_amdgcn_rcpf(W[tid][tid]);
  __syncthreads();

  // E = nu * Psi^{-1}, bf16, x-flattened
  for (int idx = tid; idx < 4096; idx += 256){
    int d = idx >> 6, e = idx & 63;
    Erow[((e >> 5) << 11) + (d << 5) + (e & 31)] = f2bf_hw(W[d][64 + e] * dinv[d]);
  }
  if (tid < 64){
    const int t = tid;
    float v = 0.f;
    for (int e = 0; e < 64; ++e) v = fmaf(W[t][64 + e], muk[e], v);
    v *= dinv[t];                    // v = (E mu_k)[t]
    Erow[4096 + t] = f2bf_hw(-2.f * v);
    Erow[4160 + t] = f2bf_hw(W[t][64 + t] * dinv[t]);
    float c2 = wsum64(v * muk[t]);
    float dg = wsum64(digammaf_((nu - (float)t) * 0.5f));
    if (t == 0){
      const float LN2   = 0.69314718055994531f;
      const float LN2PI = 1.83787706640934548f;
      float Elogdet = dg + 64.f * LN2 - ldsum;   // ldsum = logdet(Psi)
      float cst = 0.5f * (Elogdet - 64.f * LN2PI);
      c0o[k] = cst - 0.5f * c2 - 32.f / kap_a[k];
    }
  }
}

// ------------------- kernel B: main (MFMA, no LDS, no barriers) -------------
__global__ __launch_bounds__(256, 2) void main_kernel(
    const float* __restrict__ mu_t, const float* __restrict__ var_t,
    const float* __restrict__ F_t, const unsigned char* __restrict__ maskb,
    const short* __restrict__ Ebf, const float* __restrict__ c0o,
    float* __restrict__ out)
{
  const int tid = threadIdx.x;
  const int l = tid & 63;
  const int w = tid >> 6;
  const int g = l >> 4;              // k-slot group within MFMA frag
  const int kc = l & 15;             // B row (output col) / A row within tile
  const int bt0 = blockIdx.x * 64;
  const int btg = bt0 + w * 16 + kc; // this lane's A row (global bt)

  // mask format sniff (bool bytes vs int32), block-uniform, in-bounds both ways
  const bool byteMask =
      __any((maskb[4 * l + 1] | maskb[4 * l + 2] | maskb[4 * l + 3]) != 0);

  const float* Frow   = F_t  + (size_t)btg * 512;   // [d][r]
  const float* murow  = mu_t + (size_t)btg * 64;
  const float* varrow = var_t + (size_t)btg * 64;

  f32x4 acc0 = {0.f, 0.f, 0.f, 0.f};
  f32x4 acc1 = {0.f, 0.f, 0.f, 0.f};
  f32x4 acc2 = {0.f, 0.f, 0.f, 0.f};

  const short* bpBase = Ebf + kc * KDIM + g * 8;

  for (int h = 0; h < 2; ++h){
    // register cache: this lane's 8 e-columns of F, and mu[e]
    const int e0 = h * 32 + g * 8;
    float Fe[8][8], mue[8];
    #pragma unroll
    for (int q = 0; q < 8; ++q){
      f32x4 fa = *(const f32x4*)(Frow + (e0 + q) * 8);
      f32x4 fb = *(const f32x4*)(Frow + (e0 + q) * 8 + 4);
      #pragma unroll
      for (int r = 0; r < 4; ++r){ Fe[q][r] = fa[r]; Fe[q][4 + r] = fb[r]; }
    }
    {
      f32x4 ma = *(const f32x4*)(murow + e0);
      f32x4 mb = *(const f32x4*)(murow + e0 + 4);
      #pragma unroll
      for (int r = 0; r < 4; ++r){ mue[r] = ma[r]; mue[4 + r] = mb[r]; }
    }
    const short* bpH = bpBase + h * 2048;
    #pragma unroll 2
    for (int d = 0; d < 64; ++d){
      const short* bp = bpH + d * 32;
      bf16x8 b0 = *(const bf16x8*)(bp);
      bf16x8 b1 = *(const bf16x8*)(bp + 16 * KDIM);
      bf16x8 b2 = *(const bf16x8*)(bp + 32 * KDIM);
      f32x4 fda = *(const f32x4*)(Frow + d * 8);
      f32x4 fdb = *(const f32x4*)(Frow + d * 8 + 4);
      float mud = murow[d];
      float fd[8];
      #pragma unroll
      for (int r = 0; r < 4; ++r){ fd[r] = fda[r]; fd[4 + r] = fdb[r]; }
      float s[8];
      #pragma unroll
      for (int q = 0; q < 8; ++q) s[q] = mud * mue[q];
      #pragma unroll
      for (int r = 0; r < 8; ++r){
        #pragma unroll
        for (int q = 0; q < 8; ++q) s[q] = fmaf(fd[r], Fe[q][r], s[q]);
      }
      bfv8 ab;
      #pragma unroll
      for (int q = 0; q < 8; ++q) ab[q] = (__bf16)s[q];
      bf16x8 af = __builtin_bit_cast(bf16x8, ab);
      acc0 = __builtin_amdgcn_mfma_f32_16x16x32_bf16(af, b0, acc0, 0, 0, 0);
      acc1 = __builtin_amdgcn_mfma_f32_16x16x32_bf16(af, b1, acc1, 0, 0, 0);
      acc2 = __builtin_amdgcn_mfma_f32_16x16x32_bf16(af, b2, acc2, 0, 0, 0);
    }
  }

  // extension chunks: x in [4096,4224): A = mu (c=0,1), var (c=2,3)
  #pragma unroll
  for (int c = 0; c < 4; ++c){
    const int d0 = ((c & 1) << 5) + g * 8;
    const float* src = (c < 2) ? murow : varrow;
    f32x4 xa = *(const f32x4*)(src + d0);
    f32x4 xb = *(const f32x4*)(src + d0 + 4);
    bfv8 ab;
    #pragma unroll
    for (int r = 0; r < 4; ++r){ ab[r] = (__bf16)xa[r]; ab[4 + r] = (__bf16)xb[r]; }
    bf16x8 af = __builtin_bit_cast(bf16x8, ab);
    const short* bp = bpBase + 4096 + c * 32;
    bf16x8 b0 = *(const bf16x8*)(bp);
    bf16x8 b1 = *(const bf16x8*)(bp + 16 * KDIM);
    bf16x8 b2 = *(const bf16x8*)(bp + 32 * KDIM);
    acc0 = __builtin_amdgcn_mfma_f32_16x16x32_bf16(af, b0, acc0, 0, 0, 0);
    acc1 = __builtin_amdgcn_mfma_f32_16x16x32_bf16(af, b1, acc1, 0, 0, 0);
    acc2 = __builtin_amdgcn_mfma_f32_16x16x32_bf16(af, b2, acc2, 0, 0, 0);
  }

  // epilogue: D[m][n], m = g*4+reg (bt), n = kc (k)
  float c0a = c0o[kc];
  float c0b = c0o[16 + kc];
  float c0c = c0o[32];
  #pragma unroll
  for (int reg = 0; reg < 4; ++reg){
    int obt = bt0 + w * 16 + g * 4 + reg;
    bool mk = byteMask ? (maskb[obt] != 0) : (maskb[(size_t)4 * obt] != 0);
    float* op = out + (size_t)obt * 33;
    op[kc]      = mk ? fmaf(-0.5f, acc0[reg], c0a) : 0.f;
    op[16 + kc] = mk ? fmaf(-0.5f, acc1[reg], c0b) : 0.f;
    if (kc == 0) op[32] = mk ? fmaf(-0.5f, acc2[reg], c0c) : 0.f;
  }
}

// --------------------------- launch -----------------------------------------
extern "C" void kernel_launch(void* const* d_in, const int* in_sizes, int n_in,
                              void* d_out, int out_size, void* d_ws, size_t ws_size,
                              hipStream_t stream)
{
  const float* mu_t  = (const float*)d_in[0];
  const float* var_t = (const float*)d_in[1];
  const float* F_t   = (const float*)d_in[2];
  const float* mu_k  = (const float*)d_in[3];
  const float* Psi   = (const float*)d_in[4];
  const float* nu    = (const float*)d_in[5];
  const float* kap   = (const float*)d_in[6];
  const unsigned char* mask = (const unsigned char*)d_in[7];

  short* Ebf = (short*)d_ws;                                   // 48*4224 bf16
  float* c0o = (float*)((char*)d_ws + (size_t)NROW * KDIM * 2);
  float* outp = (float*)d_out;

  hipLaunchKernelGGL(prep_kernel, dim3(48), dim3(256), 0, stream,
                     mu_k, Psi, nu, kap, Ebf, c0o);
  hipLaunchKernelGGL(main_kernel, dim3(BT_TOTAL / 64), dim3(256), 0, stream,
                     mu_t, var_t, F_t, mask, Ebf, c0o, outp);
}

// Round 4
// 149.574 us; speedup vs baseline: 1.7157x; 1.7157x over previous
//
#include <hip/hip_runtime.h>

// ---------------------------------------------------------------------------
// StickyHDPHMMVI emission log-likelihood, MFMA formulation:
// out[bt,k] = c0_k - 0.5 * sum_x A[bt,x] * B[k,x]
//   x-chunks c=0..127: c = h*64+d, slot s=e&31 (e = h*32+s): A=S0[d][e], B=E_k[d][e]
//   c=128,129: A = mu[t],  B = -2*v_k[t]   (t = (c&1)*32 + s)
//   c=130,131: A = var[t], B = E_k[t,t]
// B stored lane-ordered: BG[((c*3 + j)*64 + kc*4 + g)*8 + q], k = j*16+kc,
// so a wave's B-fragment load is one contiguous 1KB coalesced region.
// ---------------------------------------------------------------------------

#define BT_TOTAL 32768
#define BT_BLK 32

typedef __attribute__((ext_vector_type(8))) short bf16x8;
typedef __attribute__((ext_vector_type(8))) unsigned short us8;
typedef __attribute__((ext_vector_type(8))) __bf16 bfv8;
typedef __attribute__((ext_vector_type(4))) float f32x4;

__device__ __forceinline__ float bf2f(unsigned short u){
  union { unsigned int i; float f; } c; c.i = ((unsigned int)u) << 16; return c.f;
}
__device__ __forceinline__ unsigned short f2bfu(float f){
  __bf16 h = (__bf16)f;
  return __builtin_bit_cast(unsigned short, h);
}
__device__ __forceinline__ short f2bfs(float f){
  __bf16 h = (__bf16)f;
  return __builtin_bit_cast(short, h);
}

__device__ __forceinline__ float digammaf_(float x){
  float r = 0.f;
  while (x < 6.f){ r -= 1.f / x; x += 1.f; }
  float xi = 1.f / x;
  float xi2 = xi * xi;
  return r + logf(x) - 0.5f * xi
         - xi2 * (0.083333333333f - xi2 * (0.0083333333333f - xi2 * 0.0039682539683f));
}

__device__ __forceinline__ float wsum64(float x){
  #pragma unroll
  for (int o = 32; o > 0; o >>= 1) x += __shfl_down(x, o);
  return x;  // valid in lane 0
}

// ------------------ kernel A: per-k prep (register Gauss-Jordan) ------------
__global__ __launch_bounds__(256) void prep_kernel(
    const float* __restrict__ mu_k, const float* __restrict__ Psi,
    const float* __restrict__ nu_a, const float* __restrict__ kap_a,
    short* __restrict__ BG, float* __restrict__ c0o)
{
  const int k = blockIdx.x;
  const int tid = threadIdx.x;
  if (k >= 33){
    const int kck = k - 32;                 // j=2 rows, kc 1..15 -> zero
    for (int i = tid; i < 4224; i += 256){
      int c = i >> 5, g = (i >> 3) & 3, q = i & 7;
      BG[(size_t)((c * 3 + 2) * 64 + kck * 4 + g) * 8 + q] = 0;
    }
    if (tid == 0) c0o[k] = 0.f;
    return;
  }
  const int row = tid & 63;
  const int ch  = tid >> 6;        // column chunk: cols [ch*32, ch*32+32) of 128
  const int c0  = ch << 5;

  __shared__ float pivrow[128];
  __shared__ float fcol[64];
  __shared__ float diag[64];
  __shared__ float muk[64];
  __shared__ float vpart[2][64];
  __shared__ float Ediag[64];

  float Wr[32];
  if (ch < 2){
    const float* Pg = Psi + (size_t)k * 4096 + (size_t)row * 64 + c0;
    #pragma unroll
    for (int c = 0; c < 32; ++c) Wr[c] = Pg[c];
  } else {
    #pragma unroll
    for (int c = 0; c < 32; ++c) Wr[c] = ((c0 - 64 + c) == row) ? 1.f : 0.f;
  }
  if (tid < 64) muk[tid] = mu_k[k * 64 + tid];
  __syncthreads();

  float ldsum = 0.f;
  for (int jh = 0; jh < 2; ++jh){
    #pragma unroll
    for (int jl = 0; jl < 32; ++jl){
      const int j = jh * 32 + jl;
      if (row == j){
        #pragma unroll
        for (int c = 0; c < 32; ++c) pivrow[c0 + c] = Wr[c];
      }
      if (ch == jh) fcol[row] = Wr[jl];     // static reg index
      __syncthreads();
      float piv = pivrow[j];
      float f = fcol[row] * __builtin_amdgcn_rcpf(piv);
      ldsum += logf(piv);
      if (row == j && ch == 0) diag[j] = piv;
      if (row != j){
        #pragma unroll
        for (int c = 0; c < 32; ++c) Wr[c] = fmaf(-f, pivrow[c0 + c], Wr[c]);
      }
      __syncthreads();
    }
  }

  const float nu = nu_a[k];
  const int j_k = k >> 4, kck = k & 15;

  if (ch >= 2){
    const int h = ch - 2;                   // e-half
    const float dinv = nu / diag[row];
    // v partial: sum_c E[row][h*32+c] * muk[h*32+c]
    float vp = 0.f;
    #pragma unroll
    for (int c = 0; c < 32; ++c) vp = fmaf(Wr[c], muk[h * 32 + c], vp);
    vpart[h][row] = vp * dinv;
    // E row write: chunk cBG = h*64 + row, 32 contiguous bf16 elems
    const int cBG = h * 64 + row;
    short* dst = BG + (size_t)(cBG * 192 + j_k * 64 + kck * 4) * 8;
    #pragma unroll
    for (int v4 = 0; v4 < 4; ++v4){
      bfv8 ab;
      #pragma unroll
      for (int q = 0; q < 8; ++q){
        float val = Wr[v4 * 8 + q] * dinv;
        ab[q] = (__bf16)val;
        if ((h * 32 + v4 * 8 + q) == row) Ediag[row] = val;
      }
      *(bf16x8*)(dst + v4 * 8) = __builtin_bit_cast(bf16x8, ab);
    }
  }
  __syncthreads();

  if (tid < 64){
    const int t = tid;
    float v = vpart[0][t] + vpart[1][t];
    // ext chunks: -2v at c=128+(t>>5); diag at c=130+(t>>5)
    const int g = (t >> 3) & 3, q = t & 7;
    const int cA = 128 + (t >> 5);
    const int cB = 130 + (t >> 5);
    BG[(size_t)((cA * 3 + j_k) * 64 + kck * 4 + g) * 8 + q] = f2bfs(-2.f * v);
    BG[(size_t)((cB * 3 + j_k) * 64 + kck * 4 + g) * 8 + q] = f2bfs(Ediag[t]);
    float c2 = wsum64(v * muk[t]);
    float dg = wsum64(digammaf_((nu - (float)t) * 0.5f));
    if (t == 0){
      const float LN2   = 0.69314718055994531f;
      const float LN2PI = 1.83787706640934548f;
      float Elogdet = dg + 64.f * LN2 - ldsum;
      float cst = 0.5f * (Elogdet - 64.f * LN2PI);
      c0o[k] = cst - 0.5f * c2 - 32.f / kap_a[k];
    }
  }
}

// ---------------- kernel B: main (MFMA, coalesced B, x-split) ---------------
__global__ __launch_bounds__(256, 3) void main_kernel(
    const float* __restrict__ mu_t, const float* __restrict__ var_t,
    const float* __restrict__ F_t, const unsigned char* __restrict__ maskb,
    const short* __restrict__ BG, const float* __restrict__ c0o,
    float* __restrict__ out)
{
  __shared__ unsigned short sF[BT_BLK][64][8];   // 32 KB, [bt][d^(bt&7)][r]
  __shared__ unsigned short sMu[BT_BLK][64];     // 4 KB, block-8 d-swizzle
  __shared__ unsigned short sVar[BT_BLK][64];    // 4 KB
  __shared__ float sRed[2][64][13];              // 6.5 KB (pad 13)

  const int tid = threadIdx.x;
  const int l = tid & 63;
  const int w = tid >> 6;
  const int g = l >> 4;
  const int kc = l & 15;
  const int xh = w >> 1;                 // x-half this wave computes
  const int bt0 = blockIdx.x * BT_BLK;
  const int btl = (w & 1) * 16 + kc;     // this lane's local A row
  const int btSw = btl & 7;

  const bool byteMask =
      __any((maskb[4 * l + 1] | maskb[4 * l + 2] | maskb[4 * l + 3]) != 0);

  // ---- stage mu/var/F into LDS (coalesced) ----
  {
    const float4* mg = (const float4*)(mu_t + (size_t)bt0 * 64);
    const float4* vg = (const float4*)(var_t + (size_t)bt0 * 64);
    #pragma unroll
    for (int ii = 0; ii < 2; ++ii){
      int i = tid + ii * 256;
      float4 m4 = mg[i], v4 = vg[i];
      int bt = i >> 4, d = (i & 15) << 2;
      int dsw = (((d >> 3) ^ (bt & 7)) << 3) | (d & 7);
      ushort4 mm; mm.x = f2bfu(m4.x); mm.y = f2bfu(m4.y); mm.z = f2bfu(m4.z); mm.w = f2bfu(m4.w);
      ushort4 vv; vv.x = f2bfu(v4.x); vv.y = f2bfu(v4.y); vv.z = f2bfu(v4.z); vv.w = f2bfu(v4.w);
      *(ushort4*)&sMu[bt][dsw] = mm;
      *(ushort4*)&sVar[bt][dsw] = vv;
    }
    const float4* fg = (const float4*)(F_t + (size_t)bt0 * 512);
    #pragma unroll
    for (int ii = 0; ii < 16; ++ii){
      int i = tid + ii * 256;
      float4 f = fg[i];
      int bt = i >> 7, rem = i & 127, d = rem >> 1, rb = (rem & 1) << 2;
      int dsw = d ^ (bt & 7);
      ushort4 ff; ff.x = f2bfu(f.x); ff.y = f2bfu(f.y); ff.z = f2bfu(f.z); ff.w = f2bfu(f.w);
      *(ushort4*)&sF[bt][dsw][rb] = ff;
    }
  }
  __syncthreads();

  // ---- per-lane register cache: 8 e-columns of F, mu[e] ----
  const int e0 = xh * 32 + g * 8;
  float Fe[8][8], mue[8];
  #pragma unroll
  for (int q = 0; q < 8; ++q){
    us8 fv = *(const us8*)&sF[btl][(e0 + q) ^ btSw][0];
    #pragma unroll
    for (int r = 0; r < 8; ++r) Fe[q][r] = bf2f(fv[r]);
    int e = e0 + q;
    int esw = (((e >> 3) ^ btSw) << 3) | (e & 7);
    mue[q] = bf2f(sMu[btl][esw]);
  }

  f32x4 acc0 = {0.f,0.f,0.f,0.f}, acc1 = {0.f,0.f,0.f,0.f}, acc2 = {0.f,0.f,0.f,0.f};

  const short* base = BG + (size_t)(xh * 64 * 192 + kc * 4 + g) * 8;
  bf16x8 pb0 = *(const bf16x8*)(base);
  bf16x8 pb1 = *(const bf16x8*)(base + 512);
  bf16x8 pb2 = *(const bf16x8*)(base + 1024);

  for (int d = 0; d < 64; ++d){
    bf16x8 b0 = pb0, b1 = pb1, b2 = pb2;
    base += 1536;                         // next chunk (last prefetch: ext/next-half, in-bounds)
    pb0 = *(const bf16x8*)(base);
    pb1 = *(const bf16x8*)(base + 512);
    pb2 = *(const bf16x8*)(base + 1024);

    us8 fd8 = *(const us8*)&sF[btl][d ^ btSw][0];
    int dsw8 = (((d >> 3) ^ btSw) << 3) | (d & 7);
    float mud = bf2f(sMu[btl][dsw8]);
    float fd[8], s[8];
    #pragma unroll
    for (int r = 0; r < 8; ++r) fd[r] = bf2f(fd8[r]);
    #pragma unroll
    for (int q = 0; q < 8; ++q) s[q] = mud * mue[q];
    #pragma unroll
    for (int r = 0; r < 8; ++r){
      #pragma unroll
      for (int q = 0; q < 8; ++q) s[q] = fmaf(fd[r], Fe[q][r], s[q]);
    }
    bfv8 ab;
    #pragma unroll
    for (int q = 0; q < 8; ++q) ab[q] = (__bf16)s[q];
    bf16x8 af = __builtin_bit_cast(bf16x8, ab);
    acc0 = __builtin_amdgcn_mfma_f32_16x16x32_bf16(af, b0, acc0, 0, 0, 0);
    acc1 = __builtin_amdgcn_mfma_f32_16x16x32_bf16(af, b1, acc1, 0, 0, 0);
    acc2 = __builtin_amdgcn_mfma_f32_16x16x32_bf16(af, b2, acc2, 0, 0, 0);
  }

  // ---- ext chunks: xh=0 -> {128,129} A=mu;  xh=1 -> {130,131} A=var ----
  #pragma unroll
  for (int m = 0; m < 2; ++m){
    int c = 128 + xh * 2 + m;
    const unsigned short* src = (xh == 0) ? &sMu[btl][0] : &sVar[btl][0];
    int blk = ((m * 4 + g) ^ btSw) << 3;   // block of 8 at t = m*32 + g*8
    bf16x8 af = *(const bf16x8*)&src[blk];
    const short* bp = BG + (size_t)(c * 192 + kc * 4 + g) * 8;
    bf16x8 b0 = *(const bf16x8*)(bp);
    bf16x8 b1 = *(const bf16x8*)(bp + 512);
    bf16x8 b2 = *(const bf16x8*)(bp + 1024);
    acc0 = __builtin_amdgcn_mfma_f32_16x16x32_bf16(af, b0, acc0, 0, 0, 0);
    acc1 = __builtin_amdgcn_mfma_f32_16x16x32_bf16(af, b1, acc1, 0, 0, 0);
    acc2 = __builtin_amdgcn_mfma_f32_16x16x32_bf16(af, b2, acc2, 0, 0, 0);
  }

  // ---- cross-wave x reduce + epilogue ----
  if (xh == 1){
    const int widx = w - 2;
    #pragma unroll
    for (int r = 0; r < 4; ++r){
      sRed[widx][l][r]     = acc0[r];
      sRed[widx][l][4 + r] = acc1[r];
      sRed[widx][l][8 + r] = acc2[r];
    }
  }
  __syncthreads();
  if (xh == 0){
    #pragma unroll
    for (int r = 0; r < 4; ++r){
      acc0[r] += sRed[w][l][r];
      acc1[r] += sRed[w][l][4 + r];
      acc2[r] += sRed[w][l][8 + r];
    }
    float c0a = c0o[kc];
    float c0b = c0o[16 + kc];
    float c0c = c0o[32];
    #pragma unroll
    for (int reg = 0; reg < 4; ++reg){
      int obt = bt0 + (w & 1) * 16 + g * 4 + reg;
      bool mk = byteMask ? (maskb[obt] != 0) : (maskb[(size_t)4 * obt] != 0);
      float* op = out + (size_t)obt * 33;
      op[kc]      = mk ? fmaf(-0.5f, acc0[reg], c0a) : 0.f;
      op[16 + kc] = mk ? fmaf(-0.5f, acc1[reg], c0b) : 0.f;
      if (kc == 0) op[32] = mk ? fmaf(-0.5f, acc2[reg], c0c) : 0.f;
    }
  }
}

// --------------------------- launch -----------------------------------------
extern "C" void kernel_launch(void* const* d_in, const int* in_sizes, int n_in,
                              void* d_out, int out_size, void* d_ws, size_t ws_size,
                              hipStream_t stream)
{
  const float* mu_t  = (const float*)d_in[0];
  const float* var_t = (const float*)d_in[1];
  const float* F_t   = (const float*)d_in[2];
  const float* mu_k  = (const float*)d_in[3];
  const float* Psi   = (const float*)d_in[4];
  const float* nu    = (const float*)d_in[5];
  const float* kap   = (const float*)d_in[6];
  const unsigned char* mask = (const unsigned char*)d_in[7];

  short* BG  = (short*)d_ws;                    // 132*3*64*8 bf16 = 405504 B
  float* c0o = (float*)((char*)d_ws + (size_t)132 * 3 * 64 * 8 * 2);
  float* outp = (float*)d_out;

  hipLaunchKernelGGL(prep_kernel, dim3(48), dim3(256), 0, stream,
                     mu_k, Psi, nu, kap, BG, c0o);
  hipLaunchKernelGGL(main_kernel, dim3(BT_TOTAL / BT_BLK), dim3(256), 0, stream,
                     mu_t, var_t, F_t, mask, BG, c0o, outp);
}

// Round 5
// 93.518 us; speedup vs baseline: 2.7441x; 1.5994x over previous
//
#include <hip/hip_runtime.h>

// ---------------------------------------------------------------------------
// StickyHDPHMMVI emission log-likelihood, f16 MFMA formulation:
// out[bt,k] = c0_k - 0.5 * sum_x A[bt,x] * B[k,x]
//   x-chunks c=0..127: c = h*64+d, slot s (e = h*32+s): A=S0[d][e], B=E_k[d][e]
//   c=128,129: A = mu[t],  B = -2*v_k[t]   (t = (c-128)*32 + s)
//   c=130,131: A = var[t], B = E_k[t,t]
// B lane-ordered: BG[((c*3 + j)*64 + kc*4 + g)*8 + q], k = j*16+kc, s = g*8+q
// A built in registers via v_dot2_f32_f16 from LDS-staged f16 G=[F|mu|var].
// ---------------------------------------------------------------------------

#define BT_TOTAL 32768
#define BT_BLK 32

typedef _Float16 f16;
typedef __attribute__((ext_vector_type(8))) _Float16 f16x8;
typedef __attribute__((ext_vector_type(4))) _Float16 f16x4;
typedef __attribute__((ext_vector_type(2))) _Float16 h2;
typedef __attribute__((ext_vector_type(4))) float f32x4;

#if __has_builtin(__builtin_amdgcn_fdot2)
#define DOT2(a, b, c) __builtin_amdgcn_fdot2((a), (b), (c), false)
#else
#define DOT2(a, b, c) fmaf((float)(a)[0], (float)(b)[0], fmaf((float)(a)[1], (float)(b)[1], (c)))
#endif

__device__ __forceinline__ float digammaf_(float x){
  float r = 0.f;
  while (x < 6.f){ r -= 1.f / x; x += 1.f; }
  float xi = 1.f / x;
  float xi2 = xi * xi;
  return r + logf(x) - 0.5f * xi
         - xi2 * (0.083333333333f - xi2 * (0.0083333333333f - xi2 * 0.0039682539683f));
}

__device__ __forceinline__ float wsum64(float x){
  #pragma unroll
  for (int o = 32; o > 0; o >>= 1) x += __shfl_down(x, o);
  return x;  // valid in lane 0
}

// ---------- kernel A: per-k prep (register GJ, 1 barrier/iter) --------------
__global__ __launch_bounds__(256) void prep_kernel(
    const float* __restrict__ mu_k, const float* __restrict__ Psi,
    const float* __restrict__ nu_a, const float* __restrict__ kap_a,
    f16* __restrict__ BG, float* __restrict__ c0o)
{
  const int k = blockIdx.x;
  const int tid = threadIdx.x;
  if (k >= 33){
    const int kck = k - 32;                 // j=2 rows, kc 1..15 -> zero
    for (int i = tid; i < 4224; i += 256){
      int c = i >> 5, g = (i >> 3) & 3, q = i & 7;
      BG[(size_t)((c * 3 + 2) * 64 + kck * 4 + g) * 8 + q] = (f16)0.f;
    }
    if (tid == 0) c0o[k] = 0.f;
    return;
  }
  const int row = tid & 63;
  const int ch  = tid >> 6;        // column chunk: cols [ch*32, ch*32+32) of 128
  const int c0  = ch << 5;

  __shared__ float pr[2][128];
  __shared__ float fc[2][64];
  __shared__ float diag[64];
  __shared__ float muk[64];
  __shared__ float vpart[2][64];
  __shared__ float Ediag[64];

  float Wr[32];
  if (ch < 2){
    const float* Pg = Psi + (size_t)k * 4096 + (size_t)row * 64 + c0;
    #pragma unroll
    for (int c = 0; c < 32; ++c) Wr[c] = Pg[c];
  } else {
    #pragma unroll
    for (int c = 0; c < 32; ++c) Wr[c] = ((c0 - 64 + c) == row) ? 1.f : 0.f;
  }
  if (tid < 64) muk[tid] = mu_k[k * 64 + tid];
  // publish pivot row 0 and f-column 0
  if (row == 0){
    #pragma unroll
    for (int c = 0; c < 32; ++c) pr[0][c0 + c] = Wr[c];
  }
  if (ch == 0) fc[0][row] = Wr[0];
  __syncthreads();

  for (int jh = 0; jh < 2; ++jh){
    #pragma unroll
    for (int jl = 0; jl < 32; ++jl){
      const int j = jh * 32 + jl;
      const int cur = j & 1, nxt = cur ^ 1;
      float piv = pr[cur][j];
      float f = fc[cur][row] * __builtin_amdgcn_rcpf(piv);
      if (row == j && ch == 0) diag[j] = piv;
      if (row != j){
        #pragma unroll
        for (int c = 0; c < 32; ++c) Wr[c] = fmaf(-f, pr[cur][c0 + c], Wr[c]);
      }
      if (j < 63){
        if (row == j + 1){
          #pragma unroll
          for (int c = 0; c < 32; ++c) pr[nxt][c0 + c] = Wr[c];
        }
        if (jl < 31){ if (ch == jh)     fc[nxt][row] = Wr[jl + 1]; }
        else        { if (ch == jh + 1) fc[nxt][row] = Wr[0]; }
      }
      __syncthreads();
    }
  }

  const float nu = nu_a[k];
  const int j_k = k >> 4, kck = k & 15;

  if (ch >= 2){
    const int h = ch - 2;                   // e-half
    const float dinv = nu / diag[row];
    float vp = 0.f;
    #pragma unroll
    for (int c = 0; c < 32; ++c) vp = fmaf(Wr[c], muk[h * 32 + c], vp);
    vpart[h][row] = vp * dinv;
    const int cBG = h * 64 + row;           // chunk (d=row, e-half h)
    f16* dst = BG + (size_t)(cBG * 192 + j_k * 64 + kck * 4) * 8;
    #pragma unroll
    for (int v4 = 0; v4 < 4; ++v4){
      f16x8 ab;
      #pragma unroll
      for (int q = 0; q < 8; ++q){
        float val = Wr[v4 * 8 + q] * dinv;
        ab[q] = (f16)val;
        if ((h * 32 + v4 * 8 + q) == row) Ediag[row] = val;
      }
      *(f16x8*)(dst + v4 * 8) = ab;
    }
  }
  __syncthreads();

  if (tid < 64){
    const int t = tid;
    float v = vpart[0][t] + vpart[1][t];
    const int g = (t >> 3) & 3, q = t & 7;
    const int cA = 128 + (t >> 5);
    const int cB = 130 + (t >> 5);
    BG[(size_t)((cA * 3 + j_k) * 64 + kck * 4 + g) * 8 + q] = (f16)(-2.f * v);
    BG[(size_t)((cB * 3 + j_k) * 64 + kck * 4 + g) * 8 + q] = (f16)(Ediag[t]);
    float c2 = wsum64(v * muk[t]);
    float dg = wsum64(digammaf_((nu - (float)t) * 0.5f));
    float ld = wsum64(logf(diag[t]));
    if (t == 0){
      const float LN2   = 0.69314718055994531f;
      const float LN2PI = 1.83787706640934548f;
      float Elogdet = dg + 64.f * LN2 - ld;
      float cst = 0.5f * (Elogdet - 64.f * LN2PI);
      c0o[k] = cst - 0.5f * c2 - 32.f / kap_a[k];
    }
  }
}

// ---------------- kernel B: main (f16 MFMA + fdot2 build) -------------------
__global__ __launch_bounds__(256, 4) void main_kernel(
    const float* __restrict__ mu_t, const float* __restrict__ var_t,
    const float* __restrict__ F_t, const unsigned char* __restrict__ maskb,
    const f16* __restrict__ BG, const float* __restrict__ c0o,
    float* __restrict__ out)
{
  // rows 0..63: F[d][r]; rows 64..71: mu (8/row); rows 72..79: var. 40960 B.
  __shared__ __align__(16) f16 sG[BT_BLK][80][8];

  const int tid = threadIdx.x;
  const int l = tid & 63;
  const int w = tid >> 6;
  const int g = l >> 4;
  const int kc = l & 15;
  const int xh = w >> 1;                 // x-half this wave computes
  const int bt0 = blockIdx.x * BT_BLK;
  const int btl = (w & 1) * 16 + kc;     // this lane's local A row
  const int btSw = btl & 7;

  const bool byteMask =
      __any((maskb[4 * l + 1] | maskb[4 * l + 2] | maskb[4 * l + 3]) != 0);

  // ---- stage F / mu / var into LDS (coalesced, f32->f16) ----
  {
    const float4* fg = (const float4*)(F_t + (size_t)bt0 * 512);
    #pragma unroll
    for (int ii = 0; ii < 16; ++ii){
      int i = tid + ii * 256;
      float4 f = fg[i];
      int bt = i >> 7, rem = i & 127, d = rem >> 1, rb = (rem & 1) << 2;
      int dsw = d ^ (bt & 7);
      f16x4 ff = { (f16)f.x, (f16)f.y, (f16)f.z, (f16)f.w };
      *(f16x4*)&sG[bt][dsw][rb] = ff;
    }
    const float4* mg = (const float4*)(mu_t + (size_t)bt0 * 64);
    const float4* vg = (const float4*)(var_t + (size_t)bt0 * 64);
    #pragma unroll
    for (int ii = 0; ii < 2; ++ii){
      int i = tid + ii * 256;
      float4 m4 = mg[i], v4 = vg[i];
      int bt = i >> 4, d0 = (i & 15) << 2;
      int rsw = (d0 >> 3) ^ (bt & 7);
      f16x4 mm = { (f16)m4.x, (f16)m4.y, (f16)m4.z, (f16)m4.w };
      f16x4 vv = { (f16)v4.x, (f16)v4.y, (f16)v4.z, (f16)v4.w };
      *(f16x4*)&sG[bt][64 + rsw][d0 & 7] = mm;
      *(f16x4*)&sG[bt][72 + rsw][d0 & 7] = vv;
    }
  }
  __syncthreads();

  // ---- per-lane register cache: 8 e-columns of F (as f16 pairs), mu[e] ----
  const int e0 = xh * 32 + g * 8;
  h2 Fp[8][4];
  float mue[8];
  {
    f16x8 mrow = *(const f16x8*)&sG[btl][64 + ((e0 >> 3) ^ btSw)][0];
    #pragma unroll
    for (int q = 0; q < 8; ++q){
      f16x8 fv = *(const f16x8*)&sG[btl][(e0 + q) ^ btSw][0];
      #pragma unroll
      for (int r = 0; r < 4; ++r){ h2 p = { fv[2 * r], fv[2 * r + 1] }; Fp[q][r] = p; }
      mue[q] = (float)mrow[q];
    }
  }

  f32x4 acc0 = {0.f,0.f,0.f,0.f}, acc1 = {0.f,0.f,0.f,0.f}, acc2 = {0.f,0.f,0.f,0.f};

  const f16* base = BG + (size_t)(xh * 64 * 192 + kc * 4 + g) * 8;
  f16x8 pb0 = *(const f16x8*)(base);
  f16x8 pb1 = *(const f16x8*)(base + 512);
  f16x8 pb2 = *(const f16x8*)(base + 1024);

  f16x8 fd = *(const f16x8*)&sG[btl][0 ^ btSw][0];
  float mud = (float)sG[btl][64 + ((0 >> 3) ^ btSw)][0];

  #pragma unroll 2
  for (int d = 0; d < 64; ++d){
    f16x8 b0 = pb0, b1 = pb1, b2 = pb2;
    base += 1536;
    pb0 = *(const f16x8*)(base);
    pb1 = *(const f16x8*)(base + 512);
    pb2 = *(const f16x8*)(base + 1024);

    const int dn = (d + 1) & 63;
    f16x8 fdn = *(const f16x8*)&sG[btl][dn ^ btSw][0];
    float mudn = (float)sG[btl][64 + ((dn >> 3) ^ btSw)][dn & 7];

    h2 fp[4];
    #pragma unroll
    for (int r = 0; r < 4; ++r){ h2 p = { fd[2 * r], fd[2 * r + 1] }; fp[r] = p; }

    float s[8];
    #pragma unroll
    for (int q = 0; q < 8; ++q){
      float acc = mud * mue[q];
      #pragma unroll
      for (int r = 0; r < 4; ++r) acc = DOT2(fp[r], Fp[q][r], acc);
      s[q] = acc;
    }
    f16x8 af;
    #pragma unroll
    for (int q = 0; q < 8; ++q) af[q] = (f16)s[q];

    acc0 = __builtin_amdgcn_mfma_f32_16x16x32_f16(af, b0, acc0, 0, 0, 0);
    acc1 = __builtin_amdgcn_mfma_f32_16x16x32_f16(af, b1, acc1, 0, 0, 0);
    acc2 = __builtin_amdgcn_mfma_f32_16x16x32_f16(af, b2, acc2, 0, 0, 0);

    fd = fdn; mud = mudn;
  }

  // ---- ext chunks: xh=0 -> {128,129} A=mu;  xh=1 -> {130,131} A=var ----
  #pragma unroll
  for (int m = 0; m < 2; ++m){
    int c = 128 + xh * 2 + m;
    int rowb = (xh == 0) ? 64 : 72;
    f16x8 af = *(const f16x8*)&sG[btl][rowb + ((m * 4 + g) ^ btSw)][0];
    const f16* bp = BG + (size_t)(c * 192 + kc * 4 + g) * 8;
    f16x8 b0 = *(const f16x8*)(bp);
    f16x8 b1 = *(const f16x8*)(bp + 512);
    f16x8 b2 = *(const f16x8*)(bp + 1024);
    acc0 = __builtin_amdgcn_mfma_f32_16x16x32_f16(af, b0, acc0, 0, 0, 0);
    acc1 = __builtin_amdgcn_mfma_f32_16x16x32_f16(af, b1, acc1, 0, 0, 0);
    acc2 = __builtin_amdgcn_mfma_f32_16x16x32_f16(af, b2, acc2, 0, 0, 0);
  }

  // ---- cross-wave x reduce (sRed aliased into sG after barrier) ----
  __syncthreads();                         // all waves done reading sG
  float* sRedF = (float*)sG;               // [2][64][13]
  if (xh == 1){
    const int bofs = ((w - 2) * 64 + l) * 13;
    #pragma unroll
    for (int r = 0; r < 4; ++r){
      sRedF[bofs + r]     = acc0[r];
      sRedF[bofs + 4 + r] = acc1[r];
      sRedF[bofs + 8 + r] = acc2[r];
    }
  }
  __syncthreads();
  if (xh == 0){
    const int bofs = (w * 64 + l) * 13;
    #pragma unroll
    for (int r = 0; r < 4; ++r){
      acc0[r] += sRedF[bofs + r];
      acc1[r] += sRedF[bofs + 4 + r];
      acc2[r] += sRedF[bofs + 8 + r];
    }
    float c0a = c0o[kc];
    float c0b = c0o[16 + kc];
    float c0c = c0o[32];
    #pragma unroll
    for (int reg = 0; reg < 4; ++reg){
      int obt = bt0 + (w & 1) * 16 + g * 4 + reg;
      bool mk = byteMask ? (maskb[obt] != 0) : (maskb[(size_t)4 * obt] != 0);
      float* op = out + (size_t)obt * 33;
      op[kc]      = mk ? fmaf(-0.5f, acc0[reg], c0a) : 0.f;
      op[16 + kc] = mk ? fmaf(-0.5f, acc1[reg], c0b) : 0.f;
      if (kc == 0) op[32] = mk ? fmaf(-0.5f, acc2[reg], c0c) : 0.f;
    }
  }
}

// --------------------------- launch -----------------------------------------
extern "C" void kernel_launch(void* const* d_in, const int* in_sizes, int n_in,
                              void* d_out, int out_size, void* d_ws, size_t ws_size,
                              hipStream_t stream)
{
  const float* mu_t  = (const float*)d_in[0];
  const float* var_t = (const float*)d_in[1];
  const float* F_t   = (const float*)d_in[2];
  const float* mu_k  = (const float*)d_in[3];
  const float* Psi   = (const float*)d_in[4];
  const float* nu    = (const float*)d_in[5];
  const float* kap   = (const float*)d_in[6];
  const unsigned char* mask = (const unsigned char*)d_in[7];

  f16*   BG  = (f16*)d_ws;                      // 132*3*64*8 f16 = 405504 B
  float* c0o = (float*)((char*)d_ws + (size_t)132 * 3 * 64 * 8 * 2);
  float* outp = (float*)d_out;

  hipLaunchKernelGGL(prep_kernel, dim3(48), dim3(256), 0, stream,
                     mu_k, Psi, nu, kap, BG, c0o);
  hipLaunchKernelGGL(main_kernel, dim3(BT_TOTAL / BT_BLK), dim3(256), 0, stream,
                     mu_t, var_t, F_t, mask, BG, c0o, outp);
}